// Round 6
// baseline (10922.317 us; speedup 1.0000x reference)
//
#include <hip/hip_runtime.h>
#include <hip/hip_bf16.h>

// TSP GNN: input proj -> TransformerConv(1 head) -> 3x GatedGCN -> edge MLP score.
// fp32. Algebraic/structural optimizations:
//  - h[row]@W computed as (h@W)[row]  (node GEMM + gather, not edge GEMM)
//  - e@gWE collapsed: rank-1 => attr*uE + cE (all 3 layers upfront)
//  - CSR by target col (eids permutation; ws layout = round-4 proven footprint)
//  - gemm: 128x64 tile, 8x4/thread, As k-major (2x ds_read_b128 per k)
//  - score: k-outer, 5 j-tile register accumulators -> h gathered ONCE
//  - gated_agg: 1 col/thread, 4-edge unrolled gathers (8+ loads in flight)

#define HD 300
#define GBK 32
#define GM 128
#define GN 64
#define SJT 5   // ceil(300/64) j-tiles

// ---------------- CSR build ----------------
__global__ void zero_kernel(int* p, int n) {
    int i = blockIdx.x * 256 + threadIdx.x;
    if (i < n) p[i] = 0;
}

__global__ void count_kernel(const int* __restrict__ ei, int* __restrict__ counts, int E) {
    int e = blockIdx.x * 256 + threadIdx.x;
    if (e < E) atomicAdd(&counts[ei[E + e]], 1);   // col = target
}

__global__ __launch_bounds__(1024) void scan_kernel(const int* __restrict__ counts,
                                                    int* __restrict__ offs, int n) {
    __shared__ int sums[1024];
    int tid = threadIdx.x;
    int chunk = (n + 1023) / 1024;
    int s0 = tid * chunk;
    int s1 = min(s0 + chunk, n);
    int local = 0;
    for (int i = s0; i < s1; ++i) local += counts[i];
    sums[tid] = local;
    __syncthreads();
    for (int d = 1; d < 1024; d <<= 1) {
        int t = (tid >= d) ? sums[tid - d] : 0;
        __syncthreads();
        sums[tid] += t;
        __syncthreads();
    }
    int prefix = sums[tid] - local;  // exclusive
    int run = prefix;
    for (int i = s0; i < s1; ++i) { offs[i] = run; run += counts[i]; }
    if (tid == 1023) offs[n] = sums[1023];
}

__global__ void fill_kernel(const int* __restrict__ ei, const int* __restrict__ offs,
                            int* __restrict__ cursor, int* __restrict__ eids, int E) {
    int e = blockIdx.x * 256 + threadIdx.x;
    if (e < E) {
        int c = ei[E + e];
        int p = atomicAdd(&cursor[c], 1);
        eids[offs[c] + p] = e;
    }
}

// ---------------- node embed ----------------
__global__ void embed_kernel(const float* __restrict__ x, const float* __restrict__ W_in,
                             const float* __restrict__ b_in, float* __restrict__ h, int total) {
    int idx = blockIdx.x * 256 + threadIdx.x;
    if (idx < total) {
        int n = idx / HD;
        int j = idx - n * HD;
        h[idx] = x[n * 2] * W_in[j] + x[n * 2 + 1] * W_in[HD + j] + b_in[j];
    }
}

// ---------------- GEMM body: C[M,300] = A[M,300] @ W[300,300] + bias --------------
// 128x64 tile, 256 threads, 8x4 per thread. As k-major [32][132] (16B-aligned
// rows) so the inner loop is 3x ds_read_b128 vs 64 FMA cycles.
__device__ __forceinline__ void gemm_body(const float* __restrict__ A,
                                          const float* __restrict__ W,
                                          const float* __restrict__ bias,
                                          float* __restrict__ C, int M) {
    __shared__ float As[GBK][GM + 4];
    __shared__ float Ws[GBK][GN];
    int m0 = blockIdx.x * GM;
    int j0 = blockIdx.y * GN;
    int tid = threadIdx.x;
    int tx = tid & 15, ty = tid >> 4;     // tx: 4 cols, ty: 8 rows
    float acc[8][4] = {};
    for (int k0 = 0; k0 < HD; k0 += GBK) {
        // A tile: 128x32 = 1024 float4, 4 per thread, written transposed
        #pragma unroll
        for (int r = 0; r < 4; ++r) {
            int f4 = tid + r * 256;
            int m = f4 >> 3, kc = (f4 & 7) * 4;
            int gm = m0 + m, gk = k0 + kc;
            float4 v = make_float4(0.f, 0.f, 0.f, 0.f);
            if (gm < M) {
                if (gk + 3 < HD) v = *(const float4*)(A + (size_t)gm * HD + gk);
                else {
                    float t[4] = {0.f, 0.f, 0.f, 0.f};
                    for (int u = 0; u < 4; ++u) if (gk + u < HD) t[u] = A[(size_t)gm * HD + gk + u];
                    v = make_float4(t[0], t[1], t[2], t[3]);
                }
            }
            As[kc + 0][m] = v.x; As[kc + 1][m] = v.y; As[kc + 2][m] = v.z; As[kc + 3][m] = v.w;
        }
        // W tile [32][64]: 512 float4, 2 per thread
        #pragma unroll
        for (int r = 0; r < 2; ++r) {
            int f4 = tid + r * 256;
            int kk = f4 >> 4, jc = (f4 & 15) * 4;
            int gk = k0 + kk, gj = j0 + jc;
            float4 v = make_float4(0.f, 0.f, 0.f, 0.f);
            if (gk < HD) {
                if (gj + 3 < HD) v = *(const float4*)(W + (size_t)gk * HD + gj);
                else {
                    float t[4] = {0.f, 0.f, 0.f, 0.f};
                    for (int u = 0; u < 4; ++u) if (gj + u < HD) t[u] = W[(size_t)gk * HD + gj + u];
                    v = make_float4(t[0], t[1], t[2], t[3]);
                }
            }
            Ws[kk][jc + 0] = v.x; Ws[kk][jc + 1] = v.y; Ws[kk][jc + 2] = v.z; Ws[kk][jc + 3] = v.w;
        }
        __syncthreads();
        #pragma unroll
        for (int k = 0; k < GBK; ++k) {
            float4 a0 = *(const float4*)&As[k][ty * 8];
            float4 a1 = *(const float4*)&As[k][ty * 8 + 4];
            float4 w  = *(const float4*)&Ws[k][tx * 4];
            acc[0][0] += a0.x * w.x; acc[0][1] += a0.x * w.y; acc[0][2] += a0.x * w.z; acc[0][3] += a0.x * w.w;
            acc[1][0] += a0.y * w.x; acc[1][1] += a0.y * w.y; acc[1][2] += a0.y * w.z; acc[1][3] += a0.y * w.w;
            acc[2][0] += a0.z * w.x; acc[2][1] += a0.z * w.y; acc[2][2] += a0.z * w.z; acc[2][3] += a0.z * w.w;
            acc[3][0] += a0.w * w.x; acc[3][1] += a0.w * w.y; acc[3][2] += a0.w * w.z; acc[3][3] += a0.w * w.w;
            acc[4][0] += a1.x * w.x; acc[4][1] += a1.x * w.y; acc[4][2] += a1.x * w.z; acc[4][3] += a1.x * w.w;
            acc[5][0] += a1.y * w.x; acc[5][1] += a1.y * w.y; acc[5][2] += a1.y * w.z; acc[5][3] += a1.y * w.w;
            acc[6][0] += a1.z * w.x; acc[6][1] += a1.z * w.y; acc[6][2] += a1.z * w.z; acc[6][3] += a1.z * w.w;
            acc[7][0] += a1.w * w.x; acc[7][1] += a1.w * w.y; acc[7][2] += a1.w * w.z; acc[7][3] += a1.w * w.w;
        }
        __syncthreads();
    }
    #pragma unroll
    for (int r = 0; r < 8; ++r) {
        int gm = m0 + ty * 8 + r;
        if (gm >= M) continue;
        #pragma unroll
        for (int c = 0; c < 4; ++c) {
            int gj = j0 + tx * 4 + c;
            if (gj < HD) C[(size_t)gm * HD + gj] = acc[r][c] + bias[gj];
        }
    }
}

// 4 independent GEMMs (same A) in one launch; blockIdx.z selects weights/output.
__global__ __launch_bounds__(256) void gemm_bias4(const float* __restrict__ A,
                                                  const float* W0, const float* W1,
                                                  const float* W2, const float* W3,
                                                  const float* b0, const float* b1,
                                                  const float* b2, const float* b3,
                                                  float* C0, float* C1, float* C2, float* C3,
                                                  int M) {
    const float* W; const float* b; float* C;
    switch (blockIdx.z) {
        case 0:  W = W0; b = b0; C = C0; break;
        case 1:  W = W1; b = b1; C = C1; break;
        case 2:  W = W2; b = b2; C = C2; break;
        default: W = W3; b = b3; C = C3; break;
    }
    gemm_body(A, W, b, C, M);
}

// ---------------- attention aggregate (block per target node, 320 thr) ----------
__global__ __launch_bounds__(320) void attn_agg(const float* __restrict__ q,
                                                const float* __restrict__ k,
                                                const float* __restrict__ v,
                                                const float* __restrict__ sk,
                                                const int* __restrict__ ei,
                                                const int* __restrict__ offs,
                                                const int* __restrict__ eids,
                                                float* __restrict__ hout) {
    int n = blockIdx.x;
    int tid = threadIdx.x;
    bool act = tid < HD;
    __shared__ float qs[HD];
    __shared__ float lg[64];
    __shared__ int ss[64];
    __shared__ float sm_m, sm_s, sm_scale;
    if (act) qs[tid] = q[(size_t)n * HD + tid];
    if (tid == 0) { sm_m = -1e30f; sm_s = 0.f; }
    __syncthreads();
    int start = offs[n], end = offs[n + 1];
    float acc = 0.f;
    const float rs = 1.0f / sqrtf((float)HD);
    int wv = tid >> 6, ln = tid & 63;   // 5 waves
    for (int c0 = start; c0 < end; c0 += 64) {
        int cnt = min(64, end - c0);
        // logits: 5 waves, one edge per wave at a time
        for (int i = wv; i < cnt; i += 5) {
            int src = ei[eids[c0 + i]];
            float p = 0.f;
            const float* kr = k + (size_t)src * HD;
            for (int j = ln; j < HD; j += 64) p += qs[j] * kr[j];
            p += __shfl_xor(p, 32); p += __shfl_xor(p, 16); p += __shfl_xor(p, 8);
            p += __shfl_xor(p, 4);  p += __shfl_xor(p, 2);  p += __shfl_xor(p, 1);
            if (ln == 0) { lg[i] = p * rs; ss[i] = src; }
        }
        __syncthreads();
        // wave 0: online softmax update
        if (wv == 0) {
            float l = (ln < cnt) ? lg[ln] : -1e30f;
            float mx = l;
            for (int d = 32; d; d >>= 1) mx = fmaxf(mx, __shfl_xor(mx, d));
            float m_old = sm_m;
            float m_new = fmaxf(m_old, mx);
            float w = (ln < cnt) ? __expf(l - m_new) : 0.f;
            float sum = w;
            for (int d = 32; d; d >>= 1) sum += __shfl_xor(sum, d);
            if (ln == 0) {
                sm_scale = __expf(m_old - m_new);
                sm_s = sm_s * sm_scale + sum;
                sm_m = m_new;
            }
            if (ln < cnt) lg[ln] = w;
        }
        __syncthreads();
        acc *= sm_scale;
        #pragma unroll 4
        for (int i = 0; i < cnt; ++i) {
            float w = lg[i];
            const float* vr = v + (size_t)ss[i] * HD;
            if (act) acc += w * vr[tid];
        }
        __syncthreads();
    }
    if (act) {
        float inv = (end > start) ? 1.0f / sm_s : 0.f;
        size_t base = (size_t)n * HD;
        hout[base + tid] = acc * inv + sk[base + tid];
    }
}

// ---------------- uE/cE: rank-1 collapse of e@gWE, all 3 layers at once ----------
__global__ void edge_w_proj(const float* __restrict__ W_edge, const float* __restrict__ b_edge,
                            const float* __restrict__ gWE, const float* __restrict__ gbE,
                            float* __restrict__ uc) {
    int j = blockIdx.x;
    int l = blockIdx.y;
    const float* WE = gWE + (size_t)l * HD * HD;
    const float* bE = gbE + (size_t)l * HD;
    float* ucl = uc + (size_t)l * 2 * HD;
    int ln = threadIdx.x;  // 64
    float pu = 0.f, pc = 0.f;
    for (int kk = ln; kk < HD; kk += 64) {
        float w = WE[(size_t)kk * HD + j];
        pu += W_edge[kk] * w;
        pc += b_edge[kk] * w;
    }
    for (int d = 32; d; d >>= 1) { pu += __shfl_xor(pu, d); pc += __shfl_xor(pc, d); }
    if (ln == 0) { ucl[j] = pu; ucl[HD + j] = pc + bE[j]; }
}

// ---------------- GatedGCN aggregate: 1 col/thread, 4-edge unrolled gathers ------
__global__ __launch_bounds__(320) void gated_agg(const float* __restrict__ hA,
                                                 const float* __restrict__ hB,
                                                 const float* __restrict__ hC,
                                                 const float* __restrict__ hR,
                                                 const float* __restrict__ uc,
                                                 const int* __restrict__ ei,
                                                 const float* __restrict__ attr,
                                                 const int* __restrict__ offs,
                                                 const int* __restrict__ eids,
                                                 float* __restrict__ hout) {
    int n = blockIdx.x;
    int tid = threadIdx.x;
    bool act = tid < HD;
    int start = offs[n], end = offs[n + 1];
    size_t base = (size_t)n * HD;
    float c1 = act ? hC[base + tid] : 0.f;
    float u1 = act ? uc[tid] : 0.f;
    float e1 = act ? uc[HD + tid] : 0.f;
    float ce = c1 + e1;
    float acc = 0.f;
    int i = start;
    // 4-edge unroll: index loads then 8 row-gathers issued back-to-back
    for (; i + 4 <= end; i += 4) {
        int id0 = eids[i], id1 = eids[i + 1], id2 = eids[i + 2], id3 = eids[i + 3];
        int s0 = ei[id0], s1 = ei[id1], s2 = ei[id2], s3 = ei[id3];
        float a0 = attr[id0], a1 = attr[id1], a2 = attr[id2], a3 = attr[id3];
        size_t b0 = (size_t)s0 * HD, b1 = (size_t)s1 * HD;
        size_t b2 = (size_t)s2 * HD, b3 = (size_t)s3 * HD;
        float hb0 = act ? hB[b0 + tid] : 0.f;
        float hb1 = act ? hB[b1 + tid] : 0.f;
        float hb2 = act ? hB[b2 + tid] : 0.f;
        float hb3 = act ? hB[b3 + tid] : 0.f;
        float ha0 = act ? hA[b0 + tid] : 0.f;
        float ha1 = act ? hA[b1 + tid] : 0.f;
        float ha2 = act ? hA[b2 + tid] : 0.f;
        float ha3 = act ? hA[b3 + tid] : 0.f;
        float t0 = hb0 + ce + a0 * u1;
        float t1 = hb1 + ce + a1 * u1;
        float t2 = hb2 + ce + a2 * u1;
        float t3 = hb3 + ce + a3 * u1;
        acc += ha0 / (1.f + __expf(-t0));
        acc += ha1 / (1.f + __expf(-t1));
        acc += ha2 / (1.f + __expf(-t2));
        acc += ha3 / (1.f + __expf(-t3));
    }
    for (; i < end; ++i) {
        int id = eids[i];
        int s = ei[id];
        float a = attr[id];
        size_t sb = (size_t)s * HD;
        float hb = act ? hB[sb + tid] : 0.f;
        float ha = act ? hA[sb + tid] : 0.f;
        float t = hb + ce + a * u1;
        acc += ha / (1.f + __expf(-t));
    }
    if (act) hout[base + tid] = fmaxf(acc + hR[base + tid], 0.f);
}

// ---------------- edge scoring: k-outer, 5 j-tile register accumulators ----------
// h rows gathered ONCE per block (was 5x); As staged 10x (was 50x).
__global__ __launch_bounds__(256) void score_fused(const float* __restrict__ h,
                                                   const int* __restrict__ ei,
                                                   const float* __restrict__ mW1,
                                                   const float* __restrict__ mb1,
                                                   const float* __restrict__ mW2,
                                                   const float* __restrict__ mb2,
                                                   float* __restrict__ out, int E) {
    __shared__ float As[GBK][64 + 4];
    __shared__ float Ws[GBK][GN];
    __shared__ int rows[64], cols[64];
    int e0 = blockIdx.x * 64;
    int tid = threadIdx.x;
    if (tid < 64) { int e = e0 + tid; rows[tid] = (e < E) ? ei[e] : 0; }
    else if (tid < 128) { int t = tid - 64; int e = e0 + t; cols[t] = (e < E) ? ei[E + e] : 0; }
    __syncthreads();
    int tx = tid & 15, ty = tid >> 4;
    float acc[SJT][4][4] = {};

    for (int k0 = 0; k0 < HD; k0 += GBK) {
        // stage |h_row - h_col| once per k-tile, transposed to k-major
        #pragma unroll
        for (int r = 0; r < 2; ++r) {
            int f4 = tid + r * 256;
            int m = f4 >> 3, kc = (f4 & 7) * 4;
            int gk = k0 + kc;
            float4 a = make_float4(0.f, 0.f, 0.f, 0.f), b = a;
            int e = e0 + m;
            if (e < E) {
                const float* hr = h + (size_t)rows[m] * HD;
                const float* hc = h + (size_t)cols[m] * HD;
                if (gk + 3 < HD) {
                    a = *(const float4*)(hr + gk);
                    b = *(const float4*)(hc + gk);
                } else {
                    float ta[4] = {0.f, 0.f, 0.f, 0.f}, tb[4] = {0.f, 0.f, 0.f, 0.f};
                    for (int u = 0; u < 4; ++u) if (gk + u < HD) { ta[u] = hr[gk + u]; tb[u] = hc[gk + u]; }
                    a = make_float4(ta[0], ta[1], ta[2], ta[3]);
                    b = make_float4(tb[0], tb[1], tb[2], tb[3]);
                }
            }
            As[kc + 0][m] = fabsf(a.x - b.x);
            As[kc + 1][m] = fabsf(a.y - b.y);
            As[kc + 2][m] = fabsf(a.z - b.z);
            As[kc + 3][m] = fabsf(a.w - b.w);
        }
        #pragma unroll
        for (int j = 0; j < SJT; ++j) {
            if (j > 0) __syncthreads();   // prev FMA done reading Ws
            // mW1 tile [32][64] for this j
            #pragma unroll
            for (int r = 0; r < 2; ++r) {
                int f4 = tid + r * 256;
                int kk = f4 >> 4, jc = (f4 & 15) * 4;
                int gk = k0 + kk, gj = j * GN + jc;
                float4 v = make_float4(0.f, 0.f, 0.f, 0.f);
                if (gk < HD) {
                    if (gj + 3 < HD) v = *(const float4*)(mW1 + (size_t)gk * HD + gj);
                    else {
                        float t[4] = {0.f, 0.f, 0.f, 0.f};
                        for (int u = 0; u < 4; ++u) if (gj + u < HD) t[u] = mW1[(size_t)gk * HD + gj + u];
                        v = make_float4(t[0], t[1], t[2], t[3]);
                    }
                }
                Ws[kk][jc + 0] = v.x; Ws[kk][jc + 1] = v.y; Ws[kk][jc + 2] = v.z; Ws[kk][jc + 3] = v.w;
            }
            __syncthreads();              // As (j==0) + Ws visible
            #pragma unroll
            for (int k = 0; k < GBK; ++k) {
                float4 a = *(const float4*)&As[k][ty * 4];
                float4 w = *(const float4*)&Ws[k][tx * 4];
                acc[j][0][0] += a.x * w.x; acc[j][0][1] += a.x * w.y; acc[j][0][2] += a.x * w.z; acc[j][0][3] += a.x * w.w;
                acc[j][1][0] += a.y * w.x; acc[j][1][1] += a.y * w.y; acc[j][1][2] += a.y * w.z; acc[j][1][3] += a.y * w.w;
                acc[j][2][0] += a.z * w.x; acc[j][2][1] += a.z * w.y; acc[j][2][2] += a.z * w.z; acc[j][2][3] += a.z * w.w;
                acc[j][3][0] += a.w * w.x; acc[j][3][1] += a.w * w.y; acc[j][3][2] += a.w * w.z; acc[j][3][3] += a.w * w.w;
            }
        }
        __syncthreads();                  // all FMAs done before As/Ws overwrite
    }
    // fold: relu(acc + mb1) @ mW2, reduce across tx lanes, store once
    float p[4] = {0.f, 0.f, 0.f, 0.f};
    #pragma unroll
    for (int j = 0; j < SJT; ++j) {
        #pragma unroll
        for (int r = 0; r < 4; ++r) {
            #pragma unroll
            for (int c = 0; c < 4; ++c) {
                int gj = j * GN + tx * 4 + c;
                if (gj < HD) {
                    float o = fmaxf(acc[j][r][c] + mb1[gj], 0.f);
                    p[r] += o * mW2[gj];
                }
            }
        }
    }
    #pragma unroll
    for (int r = 0; r < 4; ++r) {
        float s = p[r];
        s += __shfl_xor(s, 1); s += __shfl_xor(s, 2);
        s += __shfl_xor(s, 4); s += __shfl_xor(s, 8);
        if (tx == 0) {
            int e = e0 + ty * 4 + r;
            if (e < E) out[e] = s + mb2[0];
        }
    }
}

// ---------------- launch ----------------
extern "C" void kernel_launch(void* const* d_in, const int* in_sizes, int n_in,
                              void* d_out, int out_size, void* d_ws, size_t ws_size,
                              hipStream_t stream) {
    const int N = in_sizes[0] / 2;
    const int E = in_sizes[2];
    const int H = HD;

    const float* x      = (const float*)d_in[0];
    const int*   ei     = (const int*)d_in[1];
    const float* attr   = (const float*)d_in[2];
    const float* W_in   = (const float*)d_in[3];
    const float* b_in   = (const float*)d_in[4];
    const float* W_edge = (const float*)d_in[5];
    const float* b_edge = (const float*)d_in[6];
    const float* Wq = (const float*)d_in[7];  const float* bq = (const float*)d_in[8];
    const float* Wk = (const float*)d_in[9];  const float* bk = (const float*)d_in[10];
    const float* Wv = (const float*)d_in[11]; const float* bv = (const float*)d_in[12];
    const float* Wsk = (const float*)d_in[13]; const float* bsk = (const float*)d_in[14];
    const float* gWA = (const float*)d_in[15]; const float* gbA = (const float*)d_in[16];
    const float* gWB = (const float*)d_in[17]; const float* gbB = (const float*)d_in[18];
    const float* gWC = (const float*)d_in[19]; const float* gbC = (const float*)d_in[20];
    const float* gWE = (const float*)d_in[21]; const float* gbE = (const float*)d_in[22];
    const float* gWr = (const float*)d_in[23]; const float* gbr = (const float*)d_in[24];
    const float* mW1 = (const float*)d_in[25]; const float* mb1 = (const float*)d_in[26];
    const float* mW2 = (const float*)d_in[27]; const float* mb2 = (const float*)d_in[28];
    float* out = (float*)d_out;

    // ws layout IDENTICAL to round-4 (proven under poison/capture/replay):
    size_t NH = (size_t)N * H;
    float* h  = (float*)d_ws;
    float* t0 = h + NH;
    float* t1 = t0 + NH;
    float* t2 = t1 + NH;
    float* t3 = t2 + NH;
    float* uc = t3 + NH;          // 3 layers x 2 x H floats (padded to 2048)
    int* counts = (int*)(uc + 2048);
    int* cursor = counts + N;
    int* offs   = cursor + N;
    int* eids   = offs + (N + 1);

    // CSR build
    zero_kernel<<<(2 * N + 255) / 256, 256, 0, stream>>>(counts, 2 * N);
    count_kernel<<<(E + 255) / 256, 256, 0, stream>>>(ei, counts, E);
    scan_kernel<<<1, 1024, 0, stream>>>(counts, offs, N);
    fill_kernel<<<(E + 255) / 256, 256, 0, stream>>>(ei, offs, cursor, eids, E);

    // input projection
    embed_kernel<<<(N * H + 255) / 256, 256, 0, stream>>>(x, W_in, b_in, h, N * H);

    // rank-1 edge projections for all 3 GatedGCN layers
    edge_w_proj<<<dim3(H, 3), 64, 0, stream>>>(W_edge, b_edge, gWE, gbE, uc);

    dim3 gn((N + GM - 1) / GM, (H + GN - 1) / GN, 4);
    // TransformerConv: q,k,v,skip in one launch
    gemm_bias4<<<gn, 256, 0, stream>>>(h, Wq, Wk, Wv, Wsk, bq, bk, bv, bsk,
                                       t0, t1, t2, t3, N);
    attn_agg<<<N, 320, 0, stream>>>(t0, t1, t2, t3, ei, offs, eids, h);

    // GatedGCN layers: A,B,C,r in one launch per layer
    for (int l = 0; l < 3; ++l) {
        size_t wo = (size_t)l * H * H;
        size_t bo = (size_t)l * H;
        gemm_bias4<<<gn, 256, 0, stream>>>(h, gWA + wo, gWB + wo, gWC + wo, gWr + wo,
                                           gbA + bo, gbB + bo, gbC + bo, gbr + bo,
                                           t0, t1, t2, t3, N);
        gated_agg<<<N, 320, 0, stream>>>(t0, t1, t2, t3, uc + (size_t)l * 2 * H,
                                         ei, attr, offs, eids, h);
    }

    // edge scoring (single pass over h, no atomics)
    score_fused<<<(E + 63) / 64, 256, 0, stream>>>(h, ei, mW1, mb1, mW2, mb2, out, E);
}

// Round 8
// 2235.426 us; speedup vs baseline: 4.8860x; 4.8860x over previous
//
#include <hip/hip_runtime.h>
#include <hip/hip_bf16.h>

// TSP GNN: input proj -> TransformerConv(1 head) -> 3x GatedGCN -> edge MLP score.
// fp32. Algebraic/structural optimizations:
//  - h[row]@W computed as (h@W)[row]  (node GEMM + gather, not edge GEMM)
//  - e@gWE collapsed: rank-1 => attr*uE + cE (all 3 layers upfront)
//  - CSR by target col (eids permutation; ws layout = round-4 proven footprint)
//  - gemm: 128x64 tile, 8x4/thread, As k-major (ds_read_b128 inner loop)
//  - score: j-outer with PAIRED j-tiles (acc0/acc1, 32 regs) + tail tile;
//    As staged 30x/block (was 50x), NO giant unroll (round-6 spill lesson:
//    VGPR=256 + 24GB scratch WRITE_SIZE from acc[5][4][4] k-outer version)
//  - gated_agg: 1 col/thread, 4-edge unrolled gathers (8+ loads in flight)

#define HD 300
#define GBK 32
#define GM 128
#define GN 64

// ---------------- CSR build ----------------
__global__ void zero_kernel(int* p, int n) {
    int i = blockIdx.x * 256 + threadIdx.x;
    if (i < n) p[i] = 0;
}

__global__ void count_kernel(const int* __restrict__ ei, int* __restrict__ counts, int E) {
    int e = blockIdx.x * 256 + threadIdx.x;
    if (e < E) atomicAdd(&counts[ei[E + e]], 1);   // col = target
}

__global__ __launch_bounds__(1024) void scan_kernel(const int* __restrict__ counts,
                                                    int* __restrict__ offs, int n) {
    __shared__ int sums[1024];
    int tid = threadIdx.x;
    int chunk = (n + 1023) / 1024;
    int s0 = tid * chunk;
    int s1 = min(s0 + chunk, n);
    int local = 0;
    for (int i = s0; i < s1; ++i) local += counts[i];
    sums[tid] = local;
    __syncthreads();
    for (int d = 1; d < 1024; d <<= 1) {
        int t = (tid >= d) ? sums[tid - d] : 0;
        __syncthreads();
        sums[tid] += t;
        __syncthreads();
    }
    int prefix = sums[tid] - local;  // exclusive
    int run = prefix;
    for (int i = s0; i < s1; ++i) { offs[i] = run; run += counts[i]; }
    if (tid == 1023) offs[n] = sums[1023];
}

__global__ void fill_kernel(const int* __restrict__ ei, const int* __restrict__ offs,
                            int* __restrict__ cursor, int* __restrict__ eids, int E) {
    int e = blockIdx.x * 256 + threadIdx.x;
    if (e < E) {
        int c = ei[E + e];
        int p = atomicAdd(&cursor[c], 1);
        eids[offs[c] + p] = e;
    }
}

// ---------------- node embed ----------------
__global__ void embed_kernel(const float* __restrict__ x, const float* __restrict__ W_in,
                             const float* __restrict__ b_in, float* __restrict__ h, int total) {
    int idx = blockIdx.x * 256 + threadIdx.x;
    if (idx < total) {
        int n = idx / HD;
        int j = idx - n * HD;
        h[idx] = x[n * 2] * W_in[j] + x[n * 2 + 1] * W_in[HD + j] + b_in[j];
    }
}

// ---------------- GEMM body: C[M,300] = A[M,300] @ W[300,300] + bias --------------
__device__ __forceinline__ void gemm_body(const float* __restrict__ A,
                                          const float* __restrict__ W,
                                          const float* __restrict__ bias,
                                          float* __restrict__ C, int M) {
    __shared__ float As[GBK][GM + 4];
    __shared__ float Ws[GBK][GN];
    int m0 = blockIdx.x * GM;
    int j0 = blockIdx.y * GN;
    int tid = threadIdx.x;
    int tx = tid & 15, ty = tid >> 4;     // tx: 4 cols, ty: 8 rows
    float acc[8][4] = {};
    for (int k0 = 0; k0 < HD; k0 += GBK) {
        // A tile: 128x32 = 1024 float4, 4 per thread, written transposed
        #pragma unroll
        for (int r = 0; r < 4; ++r) {
            int f4 = tid + r * 256;
            int m = f4 >> 3, kc = (f4 & 7) * 4;
            int gm = m0 + m, gk = k0 + kc;
            float4 v = make_float4(0.f, 0.f, 0.f, 0.f);
            if (gm < M) {
                if (gk + 3 < HD) v = *(const float4*)(A + (size_t)gm * HD + gk);
                else {
                    float t[4] = {0.f, 0.f, 0.f, 0.f};
                    for (int u = 0; u < 4; ++u) if (gk + u < HD) t[u] = A[(size_t)gm * HD + gk + u];
                    v = make_float4(t[0], t[1], t[2], t[3]);
                }
            }
            As[kc + 0][m] = v.x; As[kc + 1][m] = v.y; As[kc + 2][m] = v.z; As[kc + 3][m] = v.w;
        }
        // W tile [32][64]: 512 float4, 2 per thread
        #pragma unroll
        for (int r = 0; r < 2; ++r) {
            int f4 = tid + r * 256;
            int kk = f4 >> 4, jc = (f4 & 15) * 4;
            int gk = k0 + kk, gj = j0 + jc;
            float4 v = make_float4(0.f, 0.f, 0.f, 0.f);
            if (gk < HD) {
                if (gj + 3 < HD) v = *(const float4*)(W + (size_t)gk * HD + gj);
                else {
                    float t[4] = {0.f, 0.f, 0.f, 0.f};
                    for (int u = 0; u < 4; ++u) if (gj + u < HD) t[u] = W[(size_t)gk * HD + gj + u];
                    v = make_float4(t[0], t[1], t[2], t[3]);
                }
            }
            Ws[kk][jc + 0] = v.x; Ws[kk][jc + 1] = v.y; Ws[kk][jc + 2] = v.z; Ws[kk][jc + 3] = v.w;
        }
        __syncthreads();
        #pragma unroll
        for (int k = 0; k < GBK; ++k) {
            float4 a0 = *(const float4*)&As[k][ty * 8];
            float4 a1 = *(const float4*)&As[k][ty * 8 + 4];
            float4 w  = *(const float4*)&Ws[k][tx * 4];
            acc[0][0] += a0.x * w.x; acc[0][1] += a0.x * w.y; acc[0][2] += a0.x * w.z; acc[0][3] += a0.x * w.w;
            acc[1][0] += a0.y * w.x; acc[1][1] += a0.y * w.y; acc[1][2] += a0.y * w.z; acc[1][3] += a0.y * w.w;
            acc[2][0] += a0.z * w.x; acc[2][1] += a0.z * w.y; acc[2][2] += a0.z * w.z; acc[2][3] += a0.z * w.w;
            acc[3][0] += a0.w * w.x; acc[3][1] += a0.w * w.y; acc[3][2] += a0.w * w.z; acc[3][3] += a0.w * w.w;
            acc[4][0] += a1.x * w.x; acc[4][1] += a1.x * w.y; acc[4][2] += a1.x * w.z; acc[4][3] += a1.x * w.w;
            acc[5][0] += a1.y * w.x; acc[5][1] += a1.y * w.y; acc[5][2] += a1.y * w.z; acc[5][3] += a1.y * w.w;
            acc[6][0] += a1.z * w.x; acc[6][1] += a1.z * w.y; acc[6][2] += a1.z * w.z; acc[6][3] += a1.z * w.w;
            acc[7][0] += a1.w * w.x; acc[7][1] += a1.w * w.y; acc[7][2] += a1.w * w.z; acc[7][3] += a1.w * w.w;
        }
        __syncthreads();
    }
    #pragma unroll
    for (int r = 0; r < 8; ++r) {
        int gm = m0 + ty * 8 + r;
        if (gm >= M) continue;
        #pragma unroll
        for (int c = 0; c < 4; ++c) {
            int gj = j0 + tx * 4 + c;
            if (gj < HD) C[(size_t)gm * HD + gj] = acc[r][c] + bias[gj];
        }
    }
}

// 4 independent GEMMs (same A) in one launch; blockIdx.z selects weights/output.
__global__ __launch_bounds__(256) void gemm_bias4(const float* __restrict__ A,
                                                  const float* W0, const float* W1,
                                                  const float* W2, const float* W3,
                                                  const float* b0, const float* b1,
                                                  const float* b2, const float* b3,
                                                  float* C0, float* C1, float* C2, float* C3,
                                                  int M) {
    const float* W; const float* b; float* C;
    switch (blockIdx.z) {
        case 0:  W = W0; b = b0; C = C0; break;
        case 1:  W = W1; b = b1; C = C1; break;
        case 2:  W = W2; b = b2; C = C2; break;
        default: W = W3; b = b3; C = C3; break;
    }
    gemm_body(A, W, b, C, M);
}

// ---------------- attention aggregate (block per target node, 320 thr) ----------
__global__ __launch_bounds__(320) void attn_agg(const float* __restrict__ q,
                                                const float* __restrict__ k,
                                                const float* __restrict__ v,
                                                const float* __restrict__ sk,
                                                const int* __restrict__ ei,
                                                const int* __restrict__ offs,
                                                const int* __restrict__ eids,
                                                float* __restrict__ hout) {
    int n = blockIdx.x;
    int tid = threadIdx.x;
    bool act = tid < HD;
    __shared__ float qs[HD];
    __shared__ float lg[64];
    __shared__ int ss[64];
    __shared__ float sm_m, sm_s, sm_scale;
    if (act) qs[tid] = q[(size_t)n * HD + tid];
    if (tid == 0) { sm_m = -1e30f; sm_s = 0.f; }
    __syncthreads();
    int start = offs[n], end = offs[n + 1];
    float acc = 0.f;
    const float rs = 1.0f / sqrtf((float)HD);
    int wv = tid >> 6, ln = tid & 63;   // 5 waves
    for (int c0 = start; c0 < end; c0 += 64) {
        int cnt = min(64, end - c0);
        // logits: 5 waves, one edge per wave at a time
        for (int i = wv; i < cnt; i += 5) {
            int src = ei[eids[c0 + i]];
            float p = 0.f;
            const float* kr = k + (size_t)src * HD;
            for (int j = ln; j < HD; j += 64) p += qs[j] * kr[j];
            p += __shfl_xor(p, 32); p += __shfl_xor(p, 16); p += __shfl_xor(p, 8);
            p += __shfl_xor(p, 4);  p += __shfl_xor(p, 2);  p += __shfl_xor(p, 1);
            if (ln == 0) { lg[i] = p * rs; ss[i] = src; }
        }
        __syncthreads();
        // wave 0: online softmax update
        if (wv == 0) {
            float l = (ln < cnt) ? lg[ln] : -1e30f;
            float mx = l;
            for (int d = 32; d; d >>= 1) mx = fmaxf(mx, __shfl_xor(mx, d));
            float m_old = sm_m;
            float m_new = fmaxf(m_old, mx);
            float w = (ln < cnt) ? __expf(l - m_new) : 0.f;
            float sum = w;
            for (int d = 32; d; d >>= 1) sum += __shfl_xor(sum, d);
            if (ln == 0) {
                sm_scale = __expf(m_old - m_new);
                sm_s = sm_s * sm_scale + sum;
                sm_m = m_new;
            }
            if (ln < cnt) lg[ln] = w;
        }
        __syncthreads();
        acc *= sm_scale;
        #pragma unroll 4
        for (int i = 0; i < cnt; ++i) {
            float w = lg[i];
            const float* vr = v + (size_t)ss[i] * HD;
            if (act) acc += w * vr[tid];
        }
        __syncthreads();
    }
    if (act) {
        float inv = (end > start) ? 1.0f / sm_s : 0.f;
        size_t base = (size_t)n * HD;
        hout[base + tid] = acc * inv + sk[base + tid];
    }
}

// ---------------- uE/cE: rank-1 collapse of e@gWE, all 3 layers at once ----------
__global__ void edge_w_proj(const float* __restrict__ W_edge, const float* __restrict__ b_edge,
                            const float* __restrict__ gWE, const float* __restrict__ gbE,
                            float* __restrict__ uc) {
    int j = blockIdx.x;
    int l = blockIdx.y;
    const float* WE = gWE + (size_t)l * HD * HD;
    const float* bE = gbE + (size_t)l * HD;
    float* ucl = uc + (size_t)l * 2 * HD;
    int ln = threadIdx.x;  // 64
    float pu = 0.f, pc = 0.f;
    for (int kk = ln; kk < HD; kk += 64) {
        float w = WE[(size_t)kk * HD + j];
        pu += W_edge[kk] * w;
        pc += b_edge[kk] * w;
    }
    for (int d = 32; d; d >>= 1) { pu += __shfl_xor(pu, d); pc += __shfl_xor(pc, d); }
    if (ln == 0) { ucl[j] = pu; ucl[HD + j] = pc + bE[j]; }
}

// ---------------- GatedGCN aggregate: 1 col/thread, 4-edge unrolled gathers ------
__global__ __launch_bounds__(320) void gated_agg(const float* __restrict__ hA,
                                                 const float* __restrict__ hB,
                                                 const float* __restrict__ hC,
                                                 const float* __restrict__ hR,
                                                 const float* __restrict__ uc,
                                                 const int* __restrict__ ei,
                                                 const float* __restrict__ attr,
                                                 const int* __restrict__ offs,
                                                 const int* __restrict__ eids,
                                                 float* __restrict__ hout) {
    int n = blockIdx.x;
    int tid = threadIdx.x;
    bool act = tid < HD;
    int start = offs[n], end = offs[n + 1];
    size_t base = (size_t)n * HD;
    float c1 = act ? hC[base + tid] : 0.f;
    float u1 = act ? uc[tid] : 0.f;
    float e1 = act ? uc[HD + tid] : 0.f;
    float ce = c1 + e1;
    float acc = 0.f;
    int i = start;
    // 4-edge unroll: index loads then 8 row-gathers issued back-to-back
    for (; i + 4 <= end; i += 4) {
        int id0 = eids[i], id1 = eids[i + 1], id2 = eids[i + 2], id3 = eids[i + 3];
        int s0 = ei[id0], s1 = ei[id1], s2 = ei[id2], s3 = ei[id3];
        float a0 = attr[id0], a1 = attr[id1], a2 = attr[id2], a3 = attr[id3];
        size_t b0 = (size_t)s0 * HD, b1 = (size_t)s1 * HD;
        size_t b2 = (size_t)s2 * HD, b3 = (size_t)s3 * HD;
        float hb0 = act ? hB[b0 + tid] : 0.f;
        float hb1 = act ? hB[b1 + tid] : 0.f;
        float hb2 = act ? hB[b2 + tid] : 0.f;
        float hb3 = act ? hB[b3 + tid] : 0.f;
        float ha0 = act ? hA[b0 + tid] : 0.f;
        float ha1 = act ? hA[b1 + tid] : 0.f;
        float ha2 = act ? hA[b2 + tid] : 0.f;
        float ha3 = act ? hA[b3 + tid] : 0.f;
        float t0 = hb0 + ce + a0 * u1;
        float t1 = hb1 + ce + a1 * u1;
        float t2 = hb2 + ce + a2 * u1;
        float t3 = hb3 + ce + a3 * u1;
        acc += ha0 / (1.f + __expf(-t0));
        acc += ha1 / (1.f + __expf(-t1));
        acc += ha2 / (1.f + __expf(-t2));
        acc += ha3 / (1.f + __expf(-t3));
    }
    for (; i < end; ++i) {
        int id = eids[i];
        int s = ei[id];
        float a = attr[id];
        size_t sb = (size_t)s * HD;
        float hb = act ? hB[sb + tid] : 0.f;
        float ha = act ? hA[sb + tid] : 0.f;
        float t = hb + ce + a * u1;
        acc += ha / (1.f + __expf(-t));
    }
    if (act) hout[base + tid] = fmaxf(acc + hR[base + tid], 0.f);
}

// ---------------- edge scoring: j-outer, PAIRED j-tiles + tail ------------------
// Per pair pass: As staged once per k-tile, two Ws tiles, 32 FMA/thread/k.
// acc0/acc1 = 32 live regs, folded into p[] at end of each pass (no spill).
__global__ __launch_bounds__(256) void score_fused(const float* __restrict__ h,
                                                   const int* __restrict__ ei,
                                                   const float* __restrict__ mW1,
                                                   const float* __restrict__ mb1,
                                                   const float* __restrict__ mW2,
                                                   const float* __restrict__ mb2,
                                                   float* __restrict__ out, int E) {
    __shared__ float As[GBK][64 + 4];
    __shared__ float Ws[2][GBK][GN];
    __shared__ int rows[64], cols[64];
    int e0 = blockIdx.x * 64;
    int tid = threadIdx.x;
    if (tid < 64) { int e = e0 + tid; rows[tid] = (e < E) ? ei[e] : 0; }
    else if (tid < 128) { int t = tid - 64; int e = e0 + t; cols[t] = (e < E) ? ei[E + e] : 0; }
    __syncthreads();
    int tx = tid & 15, ty = tid >> 4;
    float p[4] = {0.f, 0.f, 0.f, 0.f};

    // ---- two pair passes: j-tiles {0,1} then {2,3} ----
    for (int jp = 0; jp < 2; ++jp) {
        int jbase = jp * 128;
        float acc0[4][4] = {};
        float acc1[4][4] = {};
        for (int k0 = 0; k0 < HD; k0 += GBK) {
            // stage |h_row - h_col| transposed to k-major
            #pragma unroll
            for (int r = 0; r < 2; ++r) {
                int f4 = tid + r * 256;
                int m = f4 >> 3, kc = (f4 & 7) * 4;
                int gk = k0 + kc;
                float4 a = make_float4(0.f, 0.f, 0.f, 0.f), b = a;
                int e = e0 + m;
                if (e < E) {
                    const float* hr = h + (size_t)rows[m] * HD;
                    const float* hc = h + (size_t)cols[m] * HD;
                    if (gk + 3 < HD) {
                        a = *(const float4*)(hr + gk);
                        b = *(const float4*)(hc + gk);
                    } else {
                        float ta[4] = {0.f, 0.f, 0.f, 0.f}, tb[4] = {0.f, 0.f, 0.f, 0.f};
                        for (int u = 0; u < 4; ++u) if (gk + u < HD) { ta[u] = hr[gk + u]; tb[u] = hc[gk + u]; }
                        a = make_float4(ta[0], ta[1], ta[2], ta[3]);
                        b = make_float4(tb[0], tb[1], tb[2], tb[3]);
                    }
                }
                As[kc + 0][m] = fabsf(a.x - b.x);
                As[kc + 1][m] = fabsf(a.y - b.y);
                As[kc + 2][m] = fabsf(a.z - b.z);
                As[kc + 3][m] = fabsf(a.w - b.w);
            }
            // stage two mW1 tiles [32][64]
            #pragma unroll
            for (int jj = 0; jj < 2; ++jj) {
                #pragma unroll
                for (int r = 0; r < 2; ++r) {
                    int f4 = tid + r * 256;
                    int kk = f4 >> 4, jc = (f4 & 15) * 4;
                    int gk = k0 + kk, gj = jbase + jj * GN + jc;
                    float4 v = make_float4(0.f, 0.f, 0.f, 0.f);
                    if (gk < HD) v = *(const float4*)(mW1 + (size_t)gk * HD + gj);  // gj <= 252 < 300
                    Ws[jj][kk][jc + 0] = v.x; Ws[jj][kk][jc + 1] = v.y;
                    Ws[jj][kk][jc + 2] = v.z; Ws[jj][kk][jc + 3] = v.w;
                }
            }
            __syncthreads();
            #pragma unroll
            for (int k = 0; k < GBK; ++k) {
                float4 a  = *(const float4*)&As[k][ty * 4];
                float4 w0 = *(const float4*)&Ws[0][k][tx * 4];
                float4 w1 = *(const float4*)&Ws[1][k][tx * 4];
                acc0[0][0] += a.x * w0.x; acc0[0][1] += a.x * w0.y; acc0[0][2] += a.x * w0.z; acc0[0][3] += a.x * w0.w;
                acc0[1][0] += a.y * w0.x; acc0[1][1] += a.y * w0.y; acc0[1][2] += a.y * w0.z; acc0[1][3] += a.y * w0.w;
                acc0[2][0] += a.z * w0.x; acc0[2][1] += a.z * w0.y; acc0[2][2] += a.z * w0.z; acc0[2][3] += a.z * w0.w;
                acc0[3][0] += a.w * w0.x; acc0[3][1] += a.w * w0.y; acc0[3][2] += a.w * w0.z; acc0[3][3] += a.w * w0.w;
                acc1[0][0] += a.x * w1.x; acc1[0][1] += a.x * w1.y; acc1[0][2] += a.x * w1.z; acc1[0][3] += a.x * w1.w;
                acc1[1][0] += a.y * w1.x; acc1[1][1] += a.y * w1.y; acc1[1][2] += a.y * w1.z; acc1[1][3] += a.y * w1.w;
                acc1[2][0] += a.z * w1.x; acc1[2][1] += a.z * w1.y; acc1[2][2] += a.z * w1.z; acc1[2][3] += a.z * w1.w;
                acc1[3][0] += a.w * w1.x; acc1[3][1] += a.w * w1.y; acc1[3][2] += a.w * w1.z; acc1[3][3] += a.w * w1.w;
            }
            __syncthreads();
        }
        // fold this pair into per-edge scalars (all gj < 256 < HD: no guard)
        #pragma unroll
        for (int r = 0; r < 4; ++r) {
            #pragma unroll
            for (int c = 0; c < 4; ++c) {
                int gj0 = jbase + tx * 4 + c;
                float o0 = fmaxf(acc0[r][c] + mb1[gj0], 0.f);
                p[r] += o0 * mW2[gj0];
                int gj1 = gj0 + GN;
                float o1 = fmaxf(acc1[r][c] + mb1[gj1], 0.f);
                p[r] += o1 * mW2[gj1];
            }
        }
    }

    // ---- tail pass: j-tile 4 (j = 256..299) ----
    {
        float acc0[4][4] = {};
        for (int k0 = 0; k0 < HD; k0 += GBK) {
            #pragma unroll
            for (int r = 0; r < 2; ++r) {
                int f4 = tid + r * 256;
                int m = f4 >> 3, kc = (f4 & 7) * 4;
                int gk = k0 + kc;
                float4 a = make_float4(0.f, 0.f, 0.f, 0.f), b = a;
                int e = e0 + m;
                if (e < E) {
                    const float* hr = h + (size_t)rows[m] * HD;
                    const float* hc = h + (size_t)cols[m] * HD;
                    if (gk + 3 < HD) {
                        a = *(const float4*)(hr + gk);
                        b = *(const float4*)(hc + gk);
                    } else {
                        float ta[4] = {0.f, 0.f, 0.f, 0.f}, tb[4] = {0.f, 0.f, 0.f, 0.f};
                        for (int u = 0; u < 4; ++u) if (gk + u < HD) { ta[u] = hr[gk + u]; tb[u] = hc[gk + u]; }
                        a = make_float4(ta[0], ta[1], ta[2], ta[3]);
                        b = make_float4(tb[0], tb[1], tb[2], tb[3]);
                    }
                }
                As[kc + 0][m] = fabsf(a.x - b.x);
                As[kc + 1][m] = fabsf(a.y - b.y);
                As[kc + 2][m] = fabsf(a.z - b.z);
                As[kc + 3][m] = fabsf(a.w - b.w);
            }
            #pragma unroll
            for (int r = 0; r < 2; ++r) {
                int f4 = tid + r * 256;
                int kk = f4 >> 4, jc = (f4 & 15) * 4;
                int gk = k0 + kk, gj = 256 + jc;
                float4 v = make_float4(0.f, 0.f, 0.f, 0.f);
                if (gk < HD) {
                    if (gj + 3 < HD) v = *(const float4*)(mW1 + (size_t)gk * HD + gj);
                    else {
                        float t[4] = {0.f, 0.f, 0.f, 0.f};
                        for (int u = 0; u < 4; ++u) if (gj + u < HD) t[u] = mW1[(size_t)gk * HD + gj + u];
                        v = make_float4(t[0], t[1], t[2], t[3]);
                    }
                }
                Ws[0][kk][jc + 0] = v.x; Ws[0][kk][jc + 1] = v.y;
                Ws[0][kk][jc + 2] = v.z; Ws[0][kk][jc + 3] = v.w;
            }
            __syncthreads();
            #pragma unroll
            for (int k = 0; k < GBK; ++k) {
                float4 a = *(const float4*)&As[k][ty * 4];
                float4 w = *(const float4*)&Ws[0][k][tx * 4];
                acc0[0][0] += a.x * w.x; acc0[0][1] += a.x * w.y; acc0[0][2] += a.x * w.z; acc0[0][3] += a.x * w.w;
                acc0[1][0] += a.y * w.x; acc0[1][1] += a.y * w.y; acc0[1][2] += a.y * w.z; acc0[1][3] += a.y * w.w;
                acc0[2][0] += a.z * w.x; acc0[2][1] += a.z * w.y; acc0[2][2] += a.z * w.z; acc0[2][3] += a.z * w.w;
                acc0[3][0] += a.w * w.x; acc0[3][1] += a.w * w.y; acc0[3][2] += a.w * w.z; acc0[3][3] += a.w * w.w;
            }
            __syncthreads();
        }
        #pragma unroll
        for (int r = 0; r < 4; ++r) {
            #pragma unroll
            for (int c = 0; c < 4; ++c) {
                int gj = 256 + tx * 4 + c;
                if (gj < HD) {
                    float o = fmaxf(acc0[r][c] + mb1[gj], 0.f);
                    p[r] += o * mW2[gj];
                }
            }
        }
    }

    // reduce across the 16 tx lanes (within-wave) and store once
    #pragma unroll
    for (int r = 0; r < 4; ++r) {
        float s = p[r];
        s += __shfl_xor(s, 1); s += __shfl_xor(s, 2);
        s += __shfl_xor(s, 4); s += __shfl_xor(s, 8);
        if (tx == 0) {
            int e = e0 + ty * 4 + r;
            if (e < E) out[e] = s + mb2[0];
        }
    }
}

// ---------------- launch ----------------
extern "C" void kernel_launch(void* const* d_in, const int* in_sizes, int n_in,
                              void* d_out, int out_size, void* d_ws, size_t ws_size,
                              hipStream_t stream) {
    const int N = in_sizes[0] / 2;
    const int E = in_sizes[2];
    const int H = HD;

    const float* x      = (const float*)d_in[0];
    const int*   ei     = (const int*)d_in[1];
    const float* attr   = (const float*)d_in[2];
    const float* W_in   = (const float*)d_in[3];
    const float* b_in   = (const float*)d_in[4];
    const float* W_edge = (const float*)d_in[5];
    const float* b_edge = (const float*)d_in[6];
    const float* Wq = (const float*)d_in[7];  const float* bq = (const float*)d_in[8];
    const float* Wk = (const float*)d_in[9];  const float* bk = (const float*)d_in[10];
    const float* Wv = (const float*)d_in[11]; const float* bv = (const float*)d_in[12];
    const float* Wsk = (const float*)d_in[13]; const float* bsk = (const float*)d_in[14];
    const float* gWA = (const float*)d_in[15]; const float* gbA = (const float*)d_in[16];
    const float* gWB = (const float*)d_in[17]; const float* gbB = (const float*)d_in[18];
    const float* gWC = (const float*)d_in[19]; const float* gbC = (const float*)d_in[20];
    const float* gWE = (const float*)d_in[21]; const float* gbE = (const float*)d_in[22];
    const float* gWr = (const float*)d_in[23]; const float* gbr = (const float*)d_in[24];
    const float* mW1 = (const float*)d_in[25]; const float* mb1 = (const float*)d_in[26];
    const float* mW2 = (const float*)d_in[27]; const float* mb2 = (const float*)d_in[28];
    float* out = (float*)d_out;

    // ws layout IDENTICAL to round-4 (proven under poison/capture/replay):
    size_t NH = (size_t)N * H;
    float* h  = (float*)d_ws;
    float* t0 = h + NH;
    float* t1 = t0 + NH;
    float* t2 = t1 + NH;
    float* t3 = t2 + NH;
    float* uc = t3 + NH;          // 3 layers x 2 x H floats (padded to 2048)
    int* counts = (int*)(uc + 2048);
    int* cursor = counts + N;
    int* offs   = cursor + N;
    int* eids   = offs + (N + 1);

    // CSR build
    zero_kernel<<<(2 * N + 255) / 256, 256, 0, stream>>>(counts, 2 * N);
    count_kernel<<<(E + 255) / 256, 256, 0, stream>>>(ei, counts, E);
    scan_kernel<<<1, 1024, 0, stream>>>(counts, offs, N);
    fill_kernel<<<(E + 255) / 256, 256, 0, stream>>>(ei, offs, cursor, eids, E);

    // input projection
    embed_kernel<<<(N * H + 255) / 256, 256, 0, stream>>>(x, W_in, b_in, h, N * H);

    // rank-1 edge projections for all 3 GatedGCN layers
    edge_w_proj<<<dim3(H, 3), 64, 0, stream>>>(W_edge, b_edge, gWE, gbE, uc);

    dim3 gn((N + GM - 1) / GM, (H + GN - 1) / GN, 4);
    // TransformerConv: q,k,v,skip in one launch
    gemm_bias4<<<gn, 256, 0, stream>>>(h, Wq, Wk, Wv, Wsk, bq, bk, bv, bsk,
                                       t0, t1, t2, t3, N);
    attn_agg<<<N, 320, 0, stream>>>(t0, t1, t2, t3, ei, offs, eids, h);

    // GatedGCN layers: A,B,C,r in one launch per layer
    for (int l = 0; l < 3; ++l) {
        size_t wo = (size_t)l * H * H;
        size_t bo = (size_t)l * H;
        gemm_bias4<<<gn, 256, 0, stream>>>(h, gWA + wo, gWB + wo, gWC + wo, gWr + wo,
                                           gbA + bo, gbB + bo, gbC + bo, gbr + bo,
                                           t0, t1, t2, t3, N);
        gated_agg<<<N, 320, 0, stream>>>(t0, t1, t2, t3, uc + (size_t)l * 2 * H,
                                         ei, attr, offs, eids, h);
    }

    // edge scoring (single pass over h, no atomics)
    score_fused<<<(E + 63) / 64, 256, 0, stream>>>(h, ei, mW1, mb1, mW2, mb2, out, E);
}